// Round 13
// baseline (151.310 us; speedup 1.0000x reference)
//
#include <hip/hip_runtime.h>
#include <math.h>

#ifndef M_PI
#define M_PI 3.14159265358979323846
#endif

typedef unsigned short u16;
typedef __attribute__((ext_vector_type(8))) short bf16x8;
typedef __attribute__((ext_vector_type(4))) float f32x4;
typedef __attribute__((ext_vector_type(4), aligned(4))) float f32x4u;  // 4B-aligned vector load
typedef __attribute__((ext_vector_type(16))) float f32x16;

#define LDW 136   // u16 stride for LDS bf16 matrices (272B rows, octets 16B-aligned)
#define LDWF 132  // f32 stride for LDS f32 matrices (528B rows, 16B-aligned)

__device__ __forceinline__ float sigma_gamma(float r) {
    float s = 1.0f / (1.0f + __expf(r * (-1.0f / 0.15f)));
    return 0.4166666666666667f * s - 0.3333333333333333f;
}

// split f32 -> bf16 hi (truncate) + bf16 lo (RNE of residual); hi+lo ~ 2^-17 rel
__device__ __forceinline__ void split1(float x, u16& h, u16& l) {
    unsigned u = __float_as_uint(x);
    unsigned hb = u & 0xffff0000u;
    h = (u16)(hb >> 16);
    float d = x - __uint_as_float(hb);
    unsigned ud = __float_as_uint(d);
    l = (u16)((ud + 0x7fffu + ((ud >> 16) & 1u)) >> 16);
}

// Fused prologue (all parts dependency-free):
//  blocks 0..63    : spectral matrices S/Q/QT (bf16 hi/lo), DINV, G
//  blocks 64..127  : BSh = pre-swizzled S-hi in B-fragment order
//                    Bswz[(s*2+hb)*128 + col][j] = S[col][hb*8+s*16+j]  (R6-verified)
//  blocks 128..2175: SG1 = sigma(theta1), SG2a = alpha_m*sigma(theta2)
__global__ __launch_bounds__(256) void k_prep_all(
    u16* __restrict__ Shi, u16* __restrict__ Slo,
    u16* __restrict__ Qhi, u16* __restrict__ Qlo,
    u16* __restrict__ QThi, u16* __restrict__ QTlo,
    float* __restrict__ DINV, float* __restrict__ G,
    u16* __restrict__ BSh,
    const float* __restrict__ th1, const float* __restrict__ th2,
    const float* __restrict__ alpha,
    float* __restrict__ SG1, float* __restrict__ SG2a) {
    const int blk = blockIdx.x;
    if (blk < 64) {
        int id = blk * 256 + threadIdx.x;
        int r = id >> 7, c = id & 127;
        u16 h, l;
        float s = 0.f, di = 0.f;
        if (r < 126 && c < 126) {
            int prod = ((r + 1) * (c + 1)) % 254;
            s = (float)sin((double)prod * (M_PI / 127.0));
            double sr = sin((double)(r + 1) * (M_PI / 254.0));
            double sc = sin((double)(c + 1) * (M_PI / 254.0));
            di = (float)(16.0 / (64516.0 * 16129.0 * 4.0 * (sr * sr + sc * sc)));
        }
        split1(s, h, l); Shi[id] = h; Slo[id] = l;
        DINV[id] = di;
        double nc = (c == 0) ? sqrt(1.0 / 128.0) : sqrt(2.0 / 128.0);
        float q = (float)(nc * cos(M_PI * (double)c * (double)(2 * r + 1) / 256.0));
        split1(q, h, l); Qhi[id] = h; Qlo[id] = l;
        double nr = (r == 0) ? sqrt(1.0 / 128.0) : sqrt(2.0 / 128.0);
        float qt = (float)(nr * cos(M_PI * (double)r * (double)(2 * c + 1) / 256.0));
        split1(qt, h, l); QThi[id] = h; QTlo[id] = l;
        double lr = 2.0 * cos(M_PI * (double)r / 128.0) - 2.0;
        double lc = 2.0 * cos(M_PI * (double)c / 128.0) - 2.0;
        G[id] = (float)pow(1.0 + 0.03 * 1e-4 * 16129.0 * (lr + lc), 34.0);
    } else if (blk < 128) {
        int id = (blk - 64) * 256 + threadIdx.x;
        int j = id & 7, chunk = id >> 3;
        int col = chunk & 127, t = chunk >> 7;
        int hb = t & 1, s = t >> 1;
        int k = hb * 8 + s * 16 + j;
        float v = 0.f;
        if (col < 126 && k < 126) {
            int prod = ((col + 1) * (k + 1)) % 254;
            v = (float)sin((double)prod * (M_PI / 127.0));  // identical to Shi path
        }
        u16 h, l;
        split1(v, h, l);
        BSh[id] = h;
    } else {
        int id = ((blk - 128) * 256 + threadIdx.x) * 4;
        int m = id >> 14;
        float al = alpha[m];
        f32x4 a = *(const f32x4*)(th1 + id);
        f32x4 b = *(const f32x4*)(th2 + id);
        f32x4 o1, o2;
#pragma unroll
        for (int j = 0; j < 4; ++j) {
            o1[j] = sigma_gamma(a[j]);
            o2[j] = al * sigma_gamma(b[j]);
        }
        *(f32x4*)(SG1 + id) = o1;
        *(f32x4*)(SG2a + id) = o2;
    }
}

// One matmul pass with 32x32x16 MFMA: C = X * W^T, stored transposed.
// GB=true: W-hi fragments come from the pre-swizzled GLOBAL array (L2-resident,
// coalesced 16B/lane, consumed once per pass -> no remat/pin pathology);
// W-lo streams from LDS. GB=false: both from LDS (MODE 0 path).
// R11/R12 structure: D prefetched before MFMA; pack before the first barrier.
template <bool DOD, bool LAST, bool GB>
__device__ __forceinline__ void mm_pass32(u16* Xhi, u16* Xlo, float* UF,
                                          const u16* WH, const u16* WL,
                                          const u16* __restrict__ BSg,
                                          const float* Dg, int rt, int ct,
                                          int l31, int hb) {
    const int colX = ct * 32 + l31;
    f32x4 dpre[4];
    if (DOD) {
#pragma unroll
        for (int g = 0; g < 4; ++g)
            dpre[g] = *(const f32x4*)(Dg + colX * 128 + rt * 32 + 8 * g + 4 * hb);
    }
    f32x16 acc;
#pragma unroll
    for (int i = 0; i < 16; ++i) acc[i] = 0.f;
    const u16* xh = Xhi + (rt * 32 + l31) * LDW + hb * 8;
    const u16* xl = Xlo + (rt * 32 + l31) * LDW + hb * 8;
    const u16* wh = GB ? nullptr : (WH + (ct * 32 + l31) * LDW + hb * 8);
    const u16* wl = WL + (ct * 32 + l31) * LDW + hb * 8;
    const u16* bsp = GB ? (BSg + hb * 1024 + colX * 8) : nullptr;
#pragma unroll
    for (int s = 0; s < 8; ++s) {
        bf16x8 ah = *(const bf16x8*)(xh + s * 16);
        bf16x8 al = *(const bf16x8*)(xl + s * 16);
        bf16x8 bh = GB ? *(const bf16x8*)(bsp + s * 2048)
                       : *(const bf16x8*)(wh + s * 16);
        bf16x8 bl = *(const bf16x8*)(wl + s * 16);
        acc = __builtin_amdgcn_mfma_f32_32x32x16_bf16(ah, bh, acc, 0, 0, 0);
        acc = __builtin_amdgcn_mfma_f32_32x32x16_bf16(al, bh, acc, 0, 0, 0);
        acc = __builtin_amdgcn_mfma_f32_32x32x16_bf16(ah, bl, acc, 0, 0, 0);
    }
    // ---- pack results BEFORE the barrier (overlaps other waves' MFMA) ----
    f32x4 o[4];
    uint2 uh[4], ul[4];
#pragma unroll
    for (int g = 0; g < 4; ++g) {
        float v0 = acc[4 * g], v1 = acc[4 * g + 1];
        float v2 = acc[4 * g + 2], v3 = acc[4 * g + 3];
        if (DOD) {
            v0 *= dpre[g][0]; v1 *= dpre[g][1];
            v2 *= dpre[g][2]; v3 *= dpre[g][3];
        }
        if (LAST) {
            o[g] = f32x4{v0, v1, v2, v3};
        } else {
            u16 h0, l0, h1, l1, h2, l2, h3, l3;
            split1(v0, h0, l0); split1(v1, h1, l1);
            split1(v2, h2, l2); split1(v3, h3, l3);
            uh[g].x = (unsigned)h0 | ((unsigned)h1 << 16);
            uh[g].y = (unsigned)h2 | ((unsigned)h3 << 16);
            ul[g].x = (unsigned)l0 | ((unsigned)l1 << 16);
            ul[g].y = (unsigned)l2 | ((unsigned)l3 << 16);
        }
    }
    __syncthreads();  // all reads of X done before transposed overwrite
#pragma unroll
    for (int g = 0; g < 4; ++g) {
        const int rbase = rt * 32 + 8 * g + 4 * hb;
        if (LAST) {
            *(f32x4*)(UF + colX * LDWF + rbase) = o[g];
        } else {
            *(uint2*)(Xhi + colX * LDW + rbase) = uh[g];
            *(uint2*)(Xlo + colX * LDW + rbase) = ul[g];
        }
    }
    __syncthreads();
}

// MODE 0: blocks 0..7 spectral smooth (inva, dlx, dly); blocks 8..135 S1a.
// MODE 1: 256 blocks (8b x 32 groups x 4m): Poisson + t-term partials -> Pp.
//         W-hi from global BSg; only W-lo staged in LDS (102KB total LDS).
// MODE 2: 8 blocks: Poisson on reduced rhs -> d_out with zero boundary.
template <int MODE>
__global__ __launch_bounds__(1024, 4) void k_mega(
    const u16* __restrict__ WHg, const u16* __restrict__ WLg,
    const u16* __restrict__ WHg2, const u16* __restrict__ WLg2,
    const u16* __restrict__ BSg,
    const float* __restrict__ Dmat,
    const float* __restrict__ src, const float* __restrict__ aux,
    const float* __restrict__ th2, const float* __restrict__ alpha,
    const float* __restrict__ dlxc, const float* __restrict__ dlyc,
    float* __restrict__ o1, float* __restrict__ o2, float* __restrict__ o3,
    float* __restrict__ o4) {
    __shared__ __align__(16) char SM[MODE == 0 ? 139264 : 104448];
    u16* Xhi = (u16*)SM;                 // 34816 B
    u16* Xlo = (u16*)(SM + 34816);       // 34816 B
    float* UF = (float*)SM;              // alias (f32, stride LDWF, final pass)
    u16* WH = (u16*)(SM + 69632);        // MODE 0: W-hi; MODE 1/2: W-lo
    u16* WL = (u16*)(MODE == 0 ? (SM + 104448) : (SM + 69632));
    float* LG = (float*)(SM + 69632);    // alias W region (MODE0 epilogue)

    const int tid = threadIdx.x;

    if (MODE == 0 && blockIdx.x >= 8) {  // ---- S1a blocks (SG1-weighted sum) ----
        float* red = (float*)SM;
        const int px0 = (blockIdx.x - 8) * 128;
        const int pl = tid & 127, mg = tid >> 7;
        float acc = 0.f;
        for (int i = 0; i < 16; ++i) {
            int m = mg * 16 + i;
            acc += alpha[m] * th2[m * 16384 + px0 + pl];
        }
        red[tid] = acc;
        __syncthreads();
        if (tid < 128) {
            float sum = 0.f;
#pragma unroll
            for (int g = 0; g < 8; ++g) sum += red[tid + g * 128];
            o4[px0 + tid] = sum;
        }
        return;
    }

    const int wave = tid >> 6, lane = tid & 63;
    const int rt = wave >> 2, ct = wave & 3;
    const int l31 = lane & 31, hb = lane >> 5;

    int b, m0;
    if (MODE == 1) { b = blockIdx.x >> 5; m0 = (blockIdx.x & 31) * 4; }
    else { b = blockIdx.x; m0 = 0; }

    // stage W
#pragma unroll
    for (int p = 0; p < 2; ++p) {
        int ch = tid + p * 1024;
        int r = ch >> 4, j0 = (ch & 15) * 8;
        if (MODE == 0)
            *(uint4*)&WH[r * LDW + j0] = *(const uint4*)(WHg + r * 128 + j0);
        *(uint4*)&WL[r * LDW + j0] = *(const uint4*)(WLg + r * 128 + j0);
    }

    float tac[16];
    if (MODE == 1) {
#pragma unroll
        for (int i = 0; i < 16; ++i) tac[i] = 0.f;
    }

    const int ML = (MODE == 1) ? 4 : 1;
    for (int mi = 0; mi < ML; ++mi) {
        // ---- init X ----
#pragma unroll
        for (int p = 0; p < 2; ++p) {
            int ch = tid + p * 1024;
            int row = ch >> 4, c0 = (ch & 15) * 8;
            float v[8];
            if (MODE == 1) {
                const float* t1 = src + (size_t)(m0 + mi) * 16384;  // SG1 slice
                const float* iv = aux + b * 16384;
                if (row < 126) {
                    int base = (row + 1) * 128 + 1 + c0;
                    f32x4u ta = *(const f32x4u*)(t1 + base);
                    f32x4u tb = *(const f32x4u*)(t1 + base + 4);
                    f32x4u ia = *(const f32x4u*)(iv + base);
                    f32x4u ib = *(const f32x4u*)(iv + base + 4);
#pragma unroll
                    for (int j = 0; j < 8; ++j) {
                        float tv = (j < 4) ? ta[j] : tb[j - 4];
                        float ivv = (j < 4) ? ia[j] : ib[j - 4];
                        v[j] = (c0 + j < 126) ? tv * ivv : 0.f;
                    }
                } else {
#pragma unroll
                    for (int j = 0; j < 8; ++j) v[j] = 0.f;
                }
            } else {
                f32x4 p0 = *(const f32x4*)(src + b * 16384 + ch * 8);
                f32x4 p1 = *(const f32x4*)(src + b * 16384 + ch * 8 + 4);
#pragma unroll
                for (int j = 0; j < 4; ++j) { v[j] = p0[j]; v[j + 4] = p1[j]; }
            }
            unsigned hw[4], lw[4];
#pragma unroll
            for (int k = 0; k < 4; ++k) {
                u16 ha, la, hbb, lb;
                split1(v[2 * k], ha, la);
                split1(v[2 * k + 1], hbb, lb);
                hw[k] = (unsigned)ha | ((unsigned)hbb << 16);
                lw[k] = (unsigned)la | ((unsigned)lb << 16);
            }
            *(uint4*)&Xhi[row * LDW + c0] = make_uint4(hw[0], hw[1], hw[2], hw[3]);
            *(uint4*)&Xlo[row * LDW + c0] = make_uint4(lw[0], lw[1], lw[2], lw[3]);
        }
        __syncthreads();

        if (MODE == 0) {
            mm_pass32<false, false, false>(Xhi, Xlo, UF, WH, WL, nullptr, nullptr, rt, ct, l31, hb);
            mm_pass32<true, false, false>(Xhi, Xlo, UF, WH, WL, nullptr, Dmat, rt, ct, l31, hb);
            // restage W = Q for passes 3/4
#pragma unroll
            for (int p = 0; p < 2; ++p) {
                int ch = tid + p * 1024;
                int r = ch >> 4, j0 = (ch & 15) * 8;
                *(uint4*)&WH[r * LDW + j0] = *(const uint4*)(WHg2 + r * 128 + j0);
                *(uint4*)&WL[r * LDW + j0] = *(const uint4*)(WLg2 + r * 128 + j0);
            }
            __syncthreads();
            mm_pass32<false, false, false>(Xhi, Xlo, UF, WH, WL, nullptr, nullptr, rt, ct, l31, hb);
            mm_pass32<false, true, false>(Xhi, Xlo, UF, WH, WL, nullptr, nullptr, rt, ct, l31, hb);
        } else {
            mm_pass32<false, false, true>(Xhi, Xlo, UF, nullptr, WL, BSg, nullptr, rt, ct, l31, hb);
            mm_pass32<true, false, true>(Xhi, Xlo, UF, nullptr, WL, BSg, Dmat, rt, ct, l31, hb);
            mm_pass32<false, false, true>(Xhi, Xlo, UF, nullptr, WL, BSg, nullptr, rt, ct, l31, hb);
            mm_pass32<false, true, true>(Xhi, Xlo, UF, nullptr, WL, BSg, nullptr, rt, ct, l31, hb);
        }
        // UF = solved field (f32, stride LDWF)

        if (MODE == 0) {
#pragma unroll
            for (int p = 0; p < 2; ++p) {
                int ch = tid + p * 1024;
                int row = ch >> 4, c0 = (ch & 15) * 8;
                f32x4 a0 = *(const f32x4*)(UF + row * LDWF + c0);
                f32x4 a1 = *(const f32x4*)(UF + row * LDWF + c0 + 4);
                f32x4 i0, i1, g0, g1;
#pragma unroll
                for (int j = 0; j < 4; ++j) {
                    i0[j] = 1.0f / a0[j]; i1[j] = 1.0f / a1[j];
                    g0[j] = logf(fmaxf(a0[j], 1e-9f));
                    g1[j] = logf(fmaxf(a1[j], 1e-9f));
                }
                *(f32x4*)(o1 + b * 16384 + ch * 8) = i0;
                *(f32x4*)(o1 + b * 16384 + ch * 8 + 4) = i1;
                *(f32x4*)(LG + row * LDWF + c0) = g0;
                *(f32x4*)(LG + row * LDWF + c0 + 4) = g1;
            }
            __syncthreads();
#pragma unroll
            for (int p = 0; p < 2; ++p) {
                int ch = tid + p * 1024;
                int i = ch >> 4, c0 = (ch & 15) * 8;
                if (i < 1 || i > 126) continue;
                f32x4 up0 = *(const f32x4*)(LG + (i + 1) * LDWF + c0);
                f32x4 up1 = *(const f32x4*)(LG + (i + 1) * LDWF + c0 + 4);
                f32x4 um0 = *(const f32x4*)(LG + (i - 1) * LDWF + c0);
                f32x4 um1 = *(const f32x4*)(LG + (i - 1) * LDWF + c0 + 4);
                float win[13];
                win[0] = (c0 > 0) ? LG[i * LDWF + c0 - 1] : 0.f;
                f32x4 va = *(const f32x4*)(LG + i * LDWF + c0);
                f32x4 vb = *(const f32x4*)(LG + i * LDWF + c0 + 4);
                f32x4 vc = *(const f32x4*)(LG + i * LDWF + c0 + 8);
#pragma unroll
                for (int j = 0; j < 4; ++j) {
                    win[1 + j] = va[j]; win[5 + j] = vb[j]; win[9 + j] = vc[j];
                }
#pragma unroll
                for (int e = 0; e < 8; ++e) {
                    int j = c0 + e;
                    if (j < 1 || j > 126) continue;
                    float upv = (e < 4) ? up0[e] : up1[e - 4];
                    float umv = (e < 4) ? um0[e] : um1[e - 4];
                    o2[b * 16384 + i * 128 + j] = 63.5f * (upv - umv);
                    o3[b * 16384 + i * 128 + j] = 63.5f * (win[e + 2] - win[e]);
                }
            }
        } else if (MODE == 1) {
            const float* t2 = th2 + (size_t)(m0 + mi) * 16384;  // SG2a slice
            const float* dxb = dlxc + b * 16384;
            const float* dyb = dlyc + b * 16384;
#pragma unroll
            for (int p = 0; p < 2; ++p) {
                int ch = tid + p * 1024;
                int i = ch >> 4, c0 = (ch & 15) * 8;
                if (i >= 126) continue;
                const int fbase = (i + 1) * 128 + c0 + 1;
                f32x4u t2a = *(const f32x4u*)(t2 + fbase);
                f32x4u t2b = *(const f32x4u*)(t2 + fbase + 4);
                f32x4u dxa = *(const f32x4u*)(dxb + fbase);
                f32x4u dxbv = *(const f32x4u*)(dxb + fbase + 4);
                f32x4u dya = *(const f32x4u*)(dyb + fbase);
                f32x4u dybv = *(const f32x4u*)(dyb + fbase + 4);
                f32x4 up0 = *(const f32x4*)(UF + (i + 1) * LDWF + c0);
                f32x4 up1 = *(const f32x4*)(UF + (i + 1) * LDWF + c0 + 4);
                f32x4 um0, um1;
                if (i > 0) {
                    um0 = *(const f32x4*)(UF + (i - 1) * LDWF + c0);
                    um1 = *(const f32x4*)(UF + (i - 1) * LDWF + c0 + 4);
                } else {
                    um0 = f32x4{0.f, 0.f, 0.f, 0.f}; um1 = um0;
                }
                float win[13];
                win[0] = (c0 > 0) ? UF[i * LDWF + c0 - 1] : 0.f;
                f32x4 va = *(const f32x4*)(UF + i * LDWF + c0);
                f32x4 vb = *(const f32x4*)(UF + i * LDWF + c0 + 4);
                f32x4 vc = *(const f32x4*)(UF + i * LDWF + c0 + 8);
#pragma unroll
                for (int j = 0; j < 4; ++j) {
                    win[1 + j] = va[j]; win[5 + j] = vb[j]; win[9 + j] = vc[j];
                }
#pragma unroll
                for (int e = 0; e < 8; ++e) {
                    int j = c0 + e;
                    if (j >= 126) continue;
                    float upv = (e < 4) ? up0[e] : up1[e - 4];
                    float umv = (e < 4) ? um0[e] : um1[e - 4];
                    float g0x = 63.5f * (upv - umv);
                    float g0y = 63.5f * (win[e + 2] - win[e]);
                    float s2a = (e < 4) ? t2a[e] : t2b[e - 4];
                    float dxv = (e < 4) ? dxa[e] : dxbv[e - 4];
                    float dyv = (e < 4) ? dya[e] : dybv[e - 4];
                    tac[p * 8 + e] += s2a * (dxv * g0x + dyv * g0y);
                }
            }
            __syncthreads();  // UF reads done before next m's init overwrites
        } else {
#pragma unroll
            for (int p = 0; p < 2; ++p) {
                int ch = tid + p * 1024;
                int r = ch >> 4, c0 = (ch & 15) * 8;
#pragma unroll
                for (int e = 0; e < 8; ++e) {
                    int c = c0 + e;
                    float v = 0.f;
                    if (r >= 1 && r <= 126 && c >= 1 && c <= 126)
                        v = UF[(r - 1) * LDWF + (c - 1)];
                    o1[b * 16384 + r * 128 + c] = v;
                }
            }
        }
    }
    if (MODE == 1) {
#pragma unroll
        for (int p = 0; p < 2; ++p) {
            int ch = tid + p * 1024;
            f32x4 w0 = {tac[p * 8], tac[p * 8 + 1], tac[p * 8 + 2], tac[p * 8 + 3]};
            f32x4 w1 = {tac[p * 8 + 4], tac[p * 8 + 5], tac[p * 8 + 6], tac[p * 8 + 7]};
            *(f32x4*)(o1 + (size_t)blockIdx.x * 16384 + ch * 8) = w0;
            *(f32x4*)(o1 + (size_t)blockIdx.x * 16384 + ch * 8 + 4) = w1;
        }
    }
}

// R2[b] = inva*S1a (interior) + sum over 32 partials; pads -> 0. f32x4 wide.
__global__ __launch_bounds__(256) void k_reduce(const float* __restrict__ Pp,
                                                const float* __restrict__ inva,
                                                const float* __restrict__ S1a,
                                                float* __restrict__ R2) {
    int id = blockIdx.x * 256 + threadIdx.x;  // 32768 quads
    int b = id >> 12;
    int k = (id & 4095) * 4;
    int r = k >> 7, c0 = k & 127;
    f32x4 v = {0.f, 0.f, 0.f, 0.f};
    if (r < 126) {
        const float* tp = Pp + (size_t)(b * 32) * 16384 + k;
#pragma unroll 4
        for (int g = 0; g < 32; ++g) {
            f32x4 t = *(const f32x4*)(tp + (size_t)g * 16384);
            v.x += t.x; v.y += t.y; v.z += t.z; v.w += t.w;
        }
        int fi = (r + 1) * 128 + c0 + 1;
        const float* ivb = inva + b * 16384;
#pragma unroll
        for (int e = 0; e < 4; ++e) {
            int c = c0 + e;
            v[e] = (c < 126) ? (v[e] + ivb[fi + e] * S1a[fi + e]) : 0.f;
        }
    }
    *(f32x4*)(R2 + (size_t)id * 4) = v;
}

extern "C" void kernel_launch(void* const* d_in, const int* in_sizes, int n_in,
                              void* d_out, int out_size, void* d_ws,
                              size_t ws_size, hipStream_t stream) {
    const float* a      = (const float*)d_in[0];
    const float* theta1 = (const float*)d_in[1];
    const float* theta2 = (const float*)d_in[2];
    const float* alpha  = (const float*)d_in[3];
    float* out = (float*)d_out;

    float* w = (float*)d_ws;
    float* DINV = w;                       // 16384
    float* G    = w + 16384;               // 16384
    float* inva = w + 32768;               // 131072
    float* dlx  = w + 163840;              // 131072
    float* dly  = w + 294912;              // 131072
    float* S1a  = w + 425984;              // 16384
    float* R2   = w + 442368;              // 131072
    float* Pp   = w + 573440;              // 4194304 (256 partial slices)
    u16* Shi  = (u16*)(w + 4767744);
    u16* Slo  = (u16*)(w + 4775936);
    u16* Qhi  = (u16*)(w + 4784128);
    u16* Qlo  = (u16*)(w + 4792320);
    u16* QThi = (u16*)(w + 4800512);
    u16* QTlo = (u16*)(w + 4808704);
    float* SG1  = w + 4816896;             // 2097152 (sigma(theta1))
    float* SG2a = w + 6914048;             // 2097152 (alpha*sigma(theta2))
    u16* BSh  = (u16*)(w + 9011200);       // 16384 u16 (pre-swizzled S-hi)

    // fused prologue: 64 prep + 64 BSh + 2048 sigma blocks
    k_prep_all<<<2176, 256, 0, stream>>>(Shi, Slo, Qhi, Qlo, QThi, QTlo,
                                         DINV, G, BSh, theta1, theta2, alpha,
                                         SG1, SG2a);

    // blocks 0-7: spectral smooth -> inva,dlx,dly; blocks 8-135: S1a (from SG1)
    k_mega<0><<<136, 1024, 0, stream>>>(QThi, QTlo, Qhi, Qlo, nullptr, G, a,
                                        nullptr, SG1, alpha, nullptr, nullptr,
                                        inva, dlx, dly, S1a);

    // stage-1: 1024 Poisson solves; W-hi from global BSh, W-lo staged LDS
    k_mega<1><<<256, 1024, 0, stream>>>(nullptr, Slo, nullptr, nullptr, BSh,
                                        DINV, SG1, inva, SG2a, alpha, dlx, dly,
                                        Pp, nullptr, nullptr, nullptr);

    k_reduce<<<128, 256, 0, stream>>>(Pp, inva, S1a, R2);

    // stage-2: 8 Poisson solves, write output with zero boundary
    k_mega<2><<<8, 1024, 0, stream>>>(nullptr, Slo, nullptr, nullptr, BSh,
                                      DINV, R2, nullptr, nullptr, nullptr,
                                      nullptr, nullptr, out, nullptr, nullptr,
                                      nullptr);
}

// Round 14
// 123.961 us; speedup vs baseline: 1.2206x; 1.2206x over previous
//
#include <hip/hip_runtime.h>
#include <math.h>

#ifndef M_PI
#define M_PI 3.14159265358979323846
#endif

typedef unsigned short u16;
typedef __attribute__((ext_vector_type(8))) short bf16x8;
typedef __attribute__((ext_vector_type(4))) float f32x4;
typedef __attribute__((ext_vector_type(4), aligned(4))) float f32x4u;  // 4B-aligned vector load
typedef __attribute__((ext_vector_type(16))) float f32x16;

#define LDW 136   // u16 stride for LDS bf16 matrices (272B rows, octets 16B-aligned)
#define LDWF 132  // f32 stride for LDS f32 matrices (528B rows, 16B-aligned)

__device__ __forceinline__ float sigma_gamma(float r) {
    float s = 1.0f / (1.0f + __expf(r * (-1.0f / 0.15f)));
    return 0.4166666666666667f * s - 0.3333333333333333f;
}

// split f32 -> bf16 hi (truncate) + bf16 lo (RNE of residual); hi+lo ~ 2^-17 rel
__device__ __forceinline__ void split1(float x, u16& h, u16& l) {
    unsigned u = __float_as_uint(x);
    unsigned hb = u & 0xffff0000u;
    h = (u16)(hb >> 16);
    float d = x - __uint_as_float(hb);
    unsigned ud = __float_as_uint(d);
    l = (u16)((ud + 0x7fffu + ((ud >> 16) & 1u)) >> 16);
}

__global__ __launch_bounds__(256) void k_prep(
    u16* __restrict__ Shi, u16* __restrict__ Slo,
    u16* __restrict__ Qhi, u16* __restrict__ Qlo,
    u16* __restrict__ QThi, u16* __restrict__ QTlo,
    float* __restrict__ DINV, float* __restrict__ G) {
    int id = blockIdx.x * 256 + threadIdx.x;
    if (id >= 16384) return;
    int r = id >> 7, c = id & 127;
    u16 h, l;
    float s = 0.f, di = 0.f;
    if (r < 126 && c < 126) {
        int prod = ((r + 1) * (c + 1)) % 254;
        s = (float)sin((double)prod * (M_PI / 127.0));
        double sr = sin((double)(r + 1) * (M_PI / 254.0));
        double sc = sin((double)(c + 1) * (M_PI / 254.0));
        di = (float)(16.0 / (64516.0 * 16129.0 * 4.0 * (sr * sr + sc * sc)));
    }
    split1(s, h, l); Shi[id] = h; Slo[id] = l;
    DINV[id] = di;
    double nc = (c == 0) ? sqrt(1.0 / 128.0) : sqrt(2.0 / 128.0);
    float q = (float)(nc * cos(M_PI * (double)c * (double)(2 * r + 1) / 256.0));
    split1(q, h, l); Qhi[id] = h; Qlo[id] = l;
    double nr = (r == 0) ? sqrt(1.0 / 128.0) : sqrt(2.0 / 128.0);
    float qt = (float)(nr * cos(M_PI * (double)r * (double)(2 * c + 1) / 256.0));
    split1(qt, h, l); QThi[id] = h; QTlo[id] = l;
    double lr = 2.0 * cos(M_PI * (double)r / 128.0) - 2.0;
    double lc = 2.0 * cos(M_PI * (double)c / 128.0) - 2.0;
    G[id] = (float)pow(1.0 + 0.03 * 1e-4 * 16129.0 * (lr + lc), 34.0);
}

// Precompute SG1 = sigma(theta1), SG2a = alpha_m * sigma(theta2): removes the
// 8x-per-batch redundant transcendental evals from the hot kernel's VALU path.
__global__ __launch_bounds__(256) void k_sg(
    const float* __restrict__ th1, const float* __restrict__ th2,
    const float* __restrict__ alpha,
    float* __restrict__ SG1, float* __restrict__ SG2a) {
    int id = (blockIdx.x * 256 + threadIdx.x) * 4;  // 2048 blocks -> 2M quads
    int m = id >> 14;
    float al = alpha[m];
    f32x4 a = *(const f32x4*)(th1 + id);
    f32x4 b = *(const f32x4*)(th2 + id);
    f32x4 o1, o2;
#pragma unroll
    for (int j = 0; j < 4; ++j) {
        o1[j] = sigma_gamma(a[j]);
        o2[j] = al * sigma_gamma(b[j]);
    }
    *(f32x4*)(SG1 + id) = o1;
    *(f32x4*)(SG2a + id) = o2;
}

// One matmul pass with 32x32x16 MFMA: C = X * W_lds^T, stored transposed.
// R11 structure: D prefetched before MFMA; split/pack before the first
// barrier; barrier-locked phase is stores-only.
template <bool DOD, bool LAST>
__device__ __forceinline__ void mm_pass32(u16* Xhi, u16* Xlo, float* UF,
                                          const u16* WH, const u16* WL,
                                          const float* Dg, int rt, int ct,
                                          int l31, int hb) {
    const int colX = ct * 32 + l31;
    f32x4 dpre[4];
    if (DOD) {
#pragma unroll
        for (int g = 0; g < 4; ++g)
            dpre[g] = *(const f32x4*)(Dg + colX * 128 + rt * 32 + 8 * g + 4 * hb);
    }
    f32x16 acc;
#pragma unroll
    for (int i = 0; i < 16; ++i) acc[i] = 0.f;
    const u16* xh = Xhi + (rt * 32 + l31) * LDW + hb * 8;
    const u16* xl = Xlo + (rt * 32 + l31) * LDW + hb * 8;
    const u16* wh = WH + (ct * 32 + l31) * LDW + hb * 8;
    const u16* wl = WL + (ct * 32 + l31) * LDW + hb * 8;
#pragma unroll
    for (int s = 0; s < 8; ++s) {
        bf16x8 ah = *(const bf16x8*)(xh + s * 16);
        bf16x8 al = *(const bf16x8*)(xl + s * 16);
        bf16x8 bh = *(const bf16x8*)(wh + s * 16);
        bf16x8 bl = *(const bf16x8*)(wl + s * 16);
        acc = __builtin_amdgcn_mfma_f32_32x32x16_bf16(ah, bh, acc, 0, 0, 0);
        acc = __builtin_amdgcn_mfma_f32_32x32x16_bf16(al, bh, acc, 0, 0, 0);
        acc = __builtin_amdgcn_mfma_f32_32x32x16_bf16(ah, bl, acc, 0, 0, 0);
    }
    // ---- pack results BEFORE the barrier (overlaps other waves' MFMA) ----
    f32x4 o[4];
    uint2 uh[4], ul[4];
#pragma unroll
    for (int g = 0; g < 4; ++g) {
        float v0 = acc[4 * g], v1 = acc[4 * g + 1];
        float v2 = acc[4 * g + 2], v3 = acc[4 * g + 3];
        if (DOD) {
            v0 *= dpre[g][0]; v1 *= dpre[g][1];
            v2 *= dpre[g][2]; v3 *= dpre[g][3];
        }
        if (LAST) {
            o[g] = f32x4{v0, v1, v2, v3};
        } else {
            u16 h0, l0, h1, l1, h2, l2, h3, l3;
            split1(v0, h0, l0); split1(v1, h1, l1);
            split1(v2, h2, l2); split1(v3, h3, l3);
            uh[g].x = (unsigned)h0 | ((unsigned)h1 << 16);
            uh[g].y = (unsigned)h2 | ((unsigned)h3 << 16);
            ul[g].x = (unsigned)l0 | ((unsigned)l1 << 16);
            ul[g].y = (unsigned)l2 | ((unsigned)l3 << 16);
        }
    }
    __syncthreads();  // all reads of X done before transposed overwrite
#pragma unroll
    for (int g = 0; g < 4; ++g) {
        const int rbase = rt * 32 + 8 * g + 4 * hb;
        if (LAST) {
            *(f32x4*)(UF + colX * LDWF + rbase) = o[g];
        } else {
            *(uint2*)(Xhi + colX * LDW + rbase) = uh[g];
            *(uint2*)(Xlo + colX * LDW + rbase) = ul[g];
        }
    }
    __syncthreads();
}

// MODE 0: blocks 0..7 spectral smooth (inva, dlx, dly); blocks 8..135 S1a
//         (from precomputed SG1).
// MODE 1: 256 blocks (8b x 32 groups x 4m): Poisson + t-term partials -> Pp.
//         src = SG1, th2 = SG2a (precomputed; init/epilogue are multiply-only).
// MODE 2: 8 blocks: Poisson on reduced rhs -> d_out with zero boundary.
template <int MODE>
__global__ __launch_bounds__(1024, 4) void k_mega(
    const u16* __restrict__ WHg, const u16* __restrict__ WLg,
    const u16* __restrict__ WHg2, const u16* __restrict__ WLg2,
    const float* __restrict__ Dmat,
    const float* __restrict__ src, const float* __restrict__ aux,
    const float* __restrict__ th2, const float* __restrict__ alpha,
    const float* __restrict__ dlxc, const float* __restrict__ dlyc,
    float* __restrict__ o1, float* __restrict__ o2, float* __restrict__ o3,
    float* __restrict__ o4) {
    __shared__ __align__(16) char SM[139264];
    u16* Xhi = (u16*)SM;                 // 34816 B
    u16* Xlo = (u16*)(SM + 34816);       // 34816 B
    float* UF = (float*)SM;              // alias (f32, stride LDWF, final pass)
    u16* WH = (u16*)(SM + 69632);
    u16* WL = (u16*)(SM + 104448);
    float* LG = (float*)(SM + 69632);    // alias W region (MODE0 epilogue)

    const int tid = threadIdx.x;

    if (MODE == 0 && blockIdx.x >= 8) {  // ---- S1a blocks (SG1-weighted sum) ----
        float* red = (float*)SM;
        const int px0 = (blockIdx.x - 8) * 128;
        const int pl = tid & 127, mg = tid >> 7;
        float acc = 0.f;
        for (int i = 0; i < 16; ++i) {
            int m = mg * 16 + i;
            acc += alpha[m] * th2[m * 16384 + px0 + pl];
        }
        red[tid] = acc;
        __syncthreads();
        if (tid < 128) {
            float sum = 0.f;
#pragma unroll
            for (int g = 0; g < 8; ++g) sum += red[tid + g * 128];
            o4[px0 + tid] = sum;
        }
        return;
    }

    const int wave = tid >> 6, lane = tid & 63;
    const int rt = wave >> 2, ct = wave & 3;
    const int l31 = lane & 31, hb = lane >> 5;

    int b, m0;
    if (MODE == 1) { b = blockIdx.x >> 5; m0 = (blockIdx.x & 31) * 4; }
    else { b = blockIdx.x; m0 = 0; }

    // stage W (2 b128 chunks per thread per matrix)
#pragma unroll
    for (int p = 0; p < 2; ++p) {
        int ch = tid + p * 1024;
        int r = ch >> 4, j0 = (ch & 15) * 8;
        *(uint4*)&WH[r * LDW + j0] = *(const uint4*)(WHg + r * 128 + j0);
        *(uint4*)&WL[r * LDW + j0] = *(const uint4*)(WLg + r * 128 + j0);
    }

    float tac[16];
    if (MODE == 1) {
#pragma unroll
        for (int i = 0; i < 16; ++i) tac[i] = 0.f;
    }

    const int ML = (MODE == 1) ? 4 : 1;
    for (int mi = 0; mi < ML; ++mi) {
        // ---- init X ----
#pragma unroll
        for (int p = 0; p < 2; ++p) {
            int ch = tid + p * 1024;
            int row = ch >> 4, c0 = (ch & 15) * 8;
            float v[8];
            if (MODE == 1) {
                const float* t1 = src + (size_t)(m0 + mi) * 16384;  // SG1 slice
                const float* iv = aux + b * 16384;
                if (row < 126) {
                    int base = (row + 1) * 128 + 1 + c0;
                    f32x4u ta = *(const f32x4u*)(t1 + base);
                    f32x4u tb = *(const f32x4u*)(t1 + base + 4);
                    f32x4u ia = *(const f32x4u*)(iv + base);
                    f32x4u ib = *(const f32x4u*)(iv + base + 4);
#pragma unroll
                    for (int j = 0; j < 8; ++j) {
                        float tv = (j < 4) ? ta[j] : tb[j - 4];
                        float ivv = (j < 4) ? ia[j] : ib[j - 4];
                        v[j] = (c0 + j < 126) ? tv * ivv : 0.f;
                    }
                } else {
#pragma unroll
                    for (int j = 0; j < 8; ++j) v[j] = 0.f;
                }
            } else {
                f32x4 p0 = *(const f32x4*)(src + b * 16384 + ch * 8);
                f32x4 p1 = *(const f32x4*)(src + b * 16384 + ch * 8 + 4);
#pragma unroll
                for (int j = 0; j < 4; ++j) { v[j] = p0[j]; v[j + 4] = p1[j]; }
            }
            unsigned hw[4], lw[4];
#pragma unroll
            for (int k = 0; k < 4; ++k) {
                u16 ha, la, hbb, lb;
                split1(v[2 * k], ha, la);
                split1(v[2 * k + 1], hbb, lb);
                hw[k] = (unsigned)ha | ((unsigned)hbb << 16);
                lw[k] = (unsigned)la | ((unsigned)lb << 16);
            }
            *(uint4*)&Xhi[row * LDW + c0] = make_uint4(hw[0], hw[1], hw[2], hw[3]);
            *(uint4*)&Xlo[row * LDW + c0] = make_uint4(lw[0], lw[1], lw[2], lw[3]);
        }
        __syncthreads();

        mm_pass32<false, false>(Xhi, Xlo, UF, WH, WL, nullptr, rt, ct, l31, hb);
        mm_pass32<true, false>(Xhi, Xlo, UF, WH, WL, Dmat, rt, ct, l31, hb);
        if (MODE == 0) {  // restage W = Q for passes 3/4
#pragma unroll
            for (int p = 0; p < 2; ++p) {
                int ch = tid + p * 1024;
                int r = ch >> 4, j0 = (ch & 15) * 8;
                *(uint4*)&WH[r * LDW + j0] = *(const uint4*)(WHg2 + r * 128 + j0);
                *(uint4*)&WL[r * LDW + j0] = *(const uint4*)(WLg2 + r * 128 + j0);
            }
            __syncthreads();
        }
        mm_pass32<false, false>(Xhi, Xlo, UF, WH, WL, nullptr, rt, ct, l31, hb);
        mm_pass32<false, true>(Xhi, Xlo, UF, WH, WL, nullptr, rt, ct, l31, hb);
        // UF = solved field (f32, stride LDWF)

        if (MODE == 0) {
#pragma unroll
            for (int p = 0; p < 2; ++p) {
                int ch = tid + p * 1024;
                int row = ch >> 4, c0 = (ch & 15) * 8;
                f32x4 a0 = *(const f32x4*)(UF + row * LDWF + c0);
                f32x4 a1 = *(const f32x4*)(UF + row * LDWF + c0 + 4);
                f32x4 i0, i1, g0, g1;
#pragma unroll
                for (int j = 0; j < 4; ++j) {
                    i0[j] = 1.0f / a0[j]; i1[j] = 1.0f / a1[j];
                    g0[j] = logf(fmaxf(a0[j], 1e-9f));
                    g1[j] = logf(fmaxf(a1[j], 1e-9f));
                }
                *(f32x4*)(o1 + b * 16384 + ch * 8) = i0;
                *(f32x4*)(o1 + b * 16384 + ch * 8 + 4) = i1;
                *(f32x4*)(LG + row * LDWF + c0) = g0;
                *(f32x4*)(LG + row * LDWF + c0 + 4) = g1;
            }
            __syncthreads();
#pragma unroll
            for (int p = 0; p < 2; ++p) {
                int ch = tid + p * 1024;
                int i = ch >> 4, c0 = (ch & 15) * 8;
                if (i < 1 || i > 126) continue;
                f32x4 up0 = *(const f32x4*)(LG + (i + 1) * LDWF + c0);
                f32x4 up1 = *(const f32x4*)(LG + (i + 1) * LDWF + c0 + 4);
                f32x4 um0 = *(const f32x4*)(LG + (i - 1) * LDWF + c0);
                f32x4 um1 = *(const f32x4*)(LG + (i - 1) * LDWF + c0 + 4);
                float win[13];
                win[0] = (c0 > 0) ? LG[i * LDWF + c0 - 1] : 0.f;
                f32x4 va = *(const f32x4*)(LG + i * LDWF + c0);
                f32x4 vb = *(const f32x4*)(LG + i * LDWF + c0 + 4);
                f32x4 vc = *(const f32x4*)(LG + i * LDWF + c0 + 8);
#pragma unroll
                for (int j = 0; j < 4; ++j) {
                    win[1 + j] = va[j]; win[5 + j] = vb[j]; win[9 + j] = vc[j];
                }
#pragma unroll
                for (int e = 0; e < 8; ++e) {
                    int j = c0 + e;
                    if (j < 1 || j > 126) continue;
                    float upv = (e < 4) ? up0[e] : up1[e - 4];
                    float umv = (e < 4) ? um0[e] : um1[e - 4];
                    o2[b * 16384 + i * 128 + j] = 63.5f * (upv - umv);
                    o3[b * 16384 + i * 128 + j] = 63.5f * (win[e + 2] - win[e]);
                }
            }
        } else if (MODE == 1) {
            const float* t2 = th2 + (size_t)(m0 + mi) * 16384;  // SG2a slice
            const float* dxb = dlxc + b * 16384;
            const float* dyb = dlyc + b * 16384;
#pragma unroll
            for (int p = 0; p < 2; ++p) {
                int ch = tid + p * 1024;
                int i = ch >> 4, c0 = (ch & 15) * 8;
                if (i >= 126) continue;
                const int fbase = (i + 1) * 128 + c0 + 1;
                f32x4u t2a = *(const f32x4u*)(t2 + fbase);
                f32x4u t2b = *(const f32x4u*)(t2 + fbase + 4);
                f32x4u dxa = *(const f32x4u*)(dxb + fbase);
                f32x4u dxbv = *(const f32x4u*)(dxb + fbase + 4);
                f32x4u dya = *(const f32x4u*)(dyb + fbase);
                f32x4u dybv = *(const f32x4u*)(dyb + fbase + 4);
                f32x4 up0 = *(const f32x4*)(UF + (i + 1) * LDWF + c0);
                f32x4 up1 = *(const f32x4*)(UF + (i + 1) * LDWF + c0 + 4);
                f32x4 um0, um1;
                if (i > 0) {
                    um0 = *(const f32x4*)(UF + (i - 1) * LDWF + c0);
                    um1 = *(const f32x4*)(UF + (i - 1) * LDWF + c0 + 4);
                } else {
                    um0 = f32x4{0.f, 0.f, 0.f, 0.f}; um1 = um0;
                }
                float win[13];
                win[0] = (c0 > 0) ? UF[i * LDWF + c0 - 1] : 0.f;
                f32x4 va = *(const f32x4*)(UF + i * LDWF + c0);
                f32x4 vb = *(const f32x4*)(UF + i * LDWF + c0 + 4);
                f32x4 vc = *(const f32x4*)(UF + i * LDWF + c0 + 8);
#pragma unroll
                for (int j = 0; j < 4; ++j) {
                    win[1 + j] = va[j]; win[5 + j] = vb[j]; win[9 + j] = vc[j];
                }
#pragma unroll
                for (int e = 0; e < 8; ++e) {
                    int j = c0 + e;
                    if (j >= 126) continue;
                    float upv = (e < 4) ? up0[e] : up1[e - 4];
                    float umv = (e < 4) ? um0[e] : um1[e - 4];
                    float g0x = 63.5f * (upv - umv);
                    float g0y = 63.5f * (win[e + 2] - win[e]);
                    float s2a = (e < 4) ? t2a[e] : t2b[e - 4];
                    float dxv = (e < 4) ? dxa[e] : dxbv[e - 4];
                    float dyv = (e < 4) ? dya[e] : dybv[e - 4];
                    tac[p * 8 + e] += s2a * (dxv * g0x + dyv * g0y);
                }
            }
            __syncthreads();  // UF reads done before next m's init overwrites
        } else {
#pragma unroll
            for (int p = 0; p < 2; ++p) {
                int ch = tid + p * 1024;
                int r = ch >> 4, c0 = (ch & 15) * 8;
#pragma unroll
                for (int e = 0; e < 8; ++e) {
                    int c = c0 + e;
                    float v = 0.f;
                    if (r >= 1 && r <= 126 && c >= 1 && c <= 126)
                        v = UF[(r - 1) * LDWF + (c - 1)];
                    o1[b * 16384 + r * 128 + c] = v;
                }
            }
        }
    }
    if (MODE == 1) {
#pragma unroll
        for (int p = 0; p < 2; ++p) {
            int ch = tid + p * 1024;
            f32x4 w0 = {tac[p * 8], tac[p * 8 + 1], tac[p * 8 + 2], tac[p * 8 + 3]};
            f32x4 w1 = {tac[p * 8 + 4], tac[p * 8 + 5], tac[p * 8 + 6], tac[p * 8 + 7]};
            *(f32x4*)(o1 + (size_t)blockIdx.x * 16384 + ch * 8) = w0;
            *(f32x4*)(o1 + (size_t)blockIdx.x * 16384 + ch * 8 + 4) = w1;
        }
    }
}

// R2[b] = inva*S1a (interior) + sum over 32 partials; pads -> 0. f32x4 wide.
__global__ __launch_bounds__(256) void k_reduce(const float* __restrict__ Pp,
                                                const float* __restrict__ inva,
                                                const float* __restrict__ S1a,
                                                float* __restrict__ R2) {
    int id = blockIdx.x * 256 + threadIdx.x;  // 32768 quads
    int b = id >> 12;
    int k = (id & 4095) * 4;
    int r = k >> 7, c0 = k & 127;
    f32x4 v = {0.f, 0.f, 0.f, 0.f};
    if (r < 126) {
        const float* tp = Pp + (size_t)(b * 32) * 16384 + k;
#pragma unroll 4
        for (int g = 0; g < 32; ++g) {
            f32x4 t = *(const f32x4*)(tp + (size_t)g * 16384);
            v.x += t.x; v.y += t.y; v.z += t.z; v.w += t.w;
        }
        int fi = (r + 1) * 128 + c0 + 1;
        const float* ivb = inva + b * 16384;
#pragma unroll
        for (int e = 0; e < 4; ++e) {
            int c = c0 + e;
            v[e] = (c < 126) ? (v[e] + ivb[fi + e] * S1a[fi + e]) : 0.f;
        }
    }
    *(f32x4*)(R2 + (size_t)id * 4) = v;
}

extern "C" void kernel_launch(void* const* d_in, const int* in_sizes, int n_in,
                              void* d_out, int out_size, void* d_ws,
                              size_t ws_size, hipStream_t stream) {
    const float* a      = (const float*)d_in[0];
    const float* theta1 = (const float*)d_in[1];
    const float* theta2 = (const float*)d_in[2];
    const float* alpha  = (const float*)d_in[3];
    float* out = (float*)d_out;

    float* w = (float*)d_ws;
    float* DINV = w;                       // 16384
    float* G    = w + 16384;               // 16384
    float* inva = w + 32768;               // 131072
    float* dlx  = w + 163840;              // 131072
    float* dly  = w + 294912;              // 131072
    float* S1a  = w + 425984;              // 16384
    float* R2   = w + 442368;              // 131072
    float* Pp   = w + 573440;              // 4194304 (256 partial slices)
    u16* Shi  = (u16*)(w + 4767744);
    u16* Slo  = (u16*)(w + 4775936);
    u16* Qhi  = (u16*)(w + 4784128);
    u16* Qlo  = (u16*)(w + 4792320);
    u16* QThi = (u16*)(w + 4800512);
    u16* QTlo = (u16*)(w + 4808704);
    float* SG1  = w + 4816896;             // 2097152 (sigma(theta1))
    float* SG2a = w + 6914048;             // 2097152 (alpha*sigma(theta2))

    k_prep<<<64, 256, 0, stream>>>(Shi, Slo, Qhi, Qlo, QThi, QTlo, DINV, G);
    k_sg<<<2048, 256, 0, stream>>>(theta1, theta2, alpha, SG1, SG2a);

    // blocks 0-7: spectral smooth -> inva,dlx,dly; blocks 8-135: S1a (from SG1)
    k_mega<0><<<136, 1024, 0, stream>>>(QThi, QTlo, Qhi, Qlo, G, a, nullptr,
                                        SG1, alpha, nullptr, nullptr,
                                        inva, dlx, dly, S1a);

    // stage-1: 1024 Poisson solves; init/epilogue read precomputed SG1/SG2a
    k_mega<1><<<256, 1024, 0, stream>>>(Shi, Slo, nullptr, nullptr, DINV,
                                        SG1, inva, SG2a, alpha, dlx, dly,
                                        Pp, nullptr, nullptr, nullptr);

    k_reduce<<<128, 256, 0, stream>>>(Pp, inva, S1a, R2);

    // stage-2: 8 Poisson solves, write output with zero boundary
    k_mega<2><<<8, 1024, 0, stream>>>(Shi, Slo, nullptr, nullptr, DINV,
                                      R2, nullptr, nullptr, nullptr, nullptr,
                                      nullptr, out, nullptr, nullptr, nullptr);
}